// Round 7
// baseline (154.596 us; speedup 1.0000x reference)
//
#include <hip/hip_runtime.h>
#include <cstdint>
#include <cstddef>
#include <type_traits>

#define B_ROWS 16384
#define D_DIM  512
#define O_DIM  512
#define BM 64
#define BN 512
#define BK 32
// W repacked fragment-major: Wf[tIdx=f*16+c][cb=o/16][lane][8 bf16]
// (tIdx<144, cb<32, lane<64). A wave's B-fragment (16 cols x 8 k) is the
// contiguous 1KB chunk at ((tIdx*32+cb)*64)*8 -- one coalesced
// global_load_dwordx4 per lane, straight to VGPR.

typedef __bf16 bf16;
typedef __attribute__((ext_vector_type(8))) bf16  bf16x8;
typedef __attribute__((ext_vector_type(4))) float f32x4;

__device__ __forceinline__ uint32_t pk2(float a, float b) {
    uint16_t ua = __builtin_bit_cast(uint16_t, (__bf16)a);
    uint16_t ub = __builtin_bit_cast(uint16_t, (__bf16)b);
    return (uint32_t)ua | ((uint32_t)ub << 16);
}

// Spline channels b0..b7 for one element as 4 packed bf16 pair-regs.
__device__ __forceinline__ void spline_pairs(float xv, uint32_t out[4]) {
    float xn = fminf(fmaxf(xv, -2.0f), 2.0f);
    float t  = (xn + 3.2f) * 2.5f;        // in [3,13]
    int   j0 = (int)t;                    // t>0 so trunc==floor
    float u  = t - (float)j0;
    float u2 = u * u, u3 = u2 * u, omu = 1.0f - u;
    const float s6 = 1.0f / 6.0f;
    float w0 = omu * omu * omu * s6;
    float w1 = (3.0f * u3 - 6.0f * u2 + 4.0f) * s6;
    float w2 = (-3.0f * u3 + 3.0f * u2 + 3.0f * u + 1.0f) * s6;
    float w3 = u3 * s6;
    uint64_t W64 = ((uint64_t)pk2(w2, w3) << 32) | pk2(w0, w1);
    int sh = (j0 - 3) * 16;               // 0..160
    uint64_t lo = W64 << (sh & 63);
    uint64_t hi = W64 >> ((64 - sh) & 63);
    uint32_t lo_lo = (uint32_t)lo, lo_hi = (uint32_t)(lo >> 32);
    uint32_t hi_lo = (uint32_t)hi, hi_hi = (uint32_t)(hi >> 32);
    bool lt64 = sh < 64, eq0 = (sh == 0), lt128 = sh < 128;
    out[0] = lt64 ? lo_lo : 0u;
    out[1] = lt64 ? lo_hi : 0u;
    out[2] = lt64 ? (eq0 ? 0u : hi_lo) : (lt128 ? lo_lo : 0u);
    out[3] = lt64 ? (eq0 ? 0u : hi_hi) : (lt128 ? lo_hi : 0u);
}

// base_weight[O,D] + spline_weight[O,D,8] fp32 -> frag-major Wf (bf16).
__global__ void pack_w_kernel(const float* __restrict__ bw,
                              const float* __restrict__ sw,
                              bf16* __restrict__ W) {
    int idx = blockIdx.x * blockDim.x + threadIdx.x;   // over O*64
    if (idx >= O_DIM * 64) return;
    int o  = idx >> 6;
    int i0 = (idx & 63) * 8;

    bf16 ob[9][8];
    const float* bwp = bw + (size_t)o * D_DIM + i0;
#pragma unroll
    for (int e = 0; e < 8; e++) {
        ob[0][e] = (bf16)bwp[e];
        const float* sp = sw + ((size_t)o * D_DIM + i0 + e) * 8;
#pragma unroll
        for (int c = 0; c < 8; c++)
            ob[c + 1][e] = (bf16)sp[c];
    }
    const int c   = i0 >> 5;              // k-chunk within channel
    const int sub = (i0 & 31) >> 3;       // quad (k-block within chunk)
    const int cb  = o >> 4;
    const int ln  = (o & 15) + sub * 16;
#pragma unroll
    for (int f = 0; f < 9; f++) {
        size_t off = ((size_t)((f * 16 + c) * 32 + cb) * 64 + ln) * 8;
        *(bf16x8*)(W + off) = *(const bf16x8*)ob[f];
    }
}

// As-only barrier: drain LDS ops, then barrier (B lives in VGPRs).
#define BARA asm volatile("s_waitcnt lgkmcnt(0)\n\ts_barrier" ::: "memory")

// R15: ILP-deepened R14. 80us = 1333 cyc/step but max pipe (B@L2) is ~570:
// ~760 cyc/step is exposed latency (2 waves/SIMD in lockstep; odd steps had
// no VALU cover; barrier every 2 steps re-convoys). Changes (math identical):
//  - 4-step barrier intervals (36 barriers): As 8 slabs (t mod 8), write
//    distance 4.
//  - A-frag pair-prefetch: even steps ds_read af for t AND t+1 (8 reads);
//    odd steps have ZERO lds ops -> MFMA fires with no lgkm wait.
//  - B triple-buffer (br[f mod 3], compile-time), load distance 2 (~2 steps
//    of flight vs ~200cyc L2 latency).
// VGPR headroom pays for it: was 96 of 256 budget at 2 waves/SIMD.
__global__ __launch_bounds__(512, 2)
void gemm_fused_kernel(const float* __restrict__ x, const bf16* __restrict__ Wf,
                       float* __restrict__ C) {
    __shared__ __align__(16) bf16 As0[BM * BK], As1[BM * BK], As2[BM * BK], As3[BM * BK];
    __shared__ __align__(16) bf16 As4[BM * BK], As5[BM * BK], As6[BM * BK], As7[BM * BK];

    const int tid  = threadIdx.x;
    const int bid  = blockIdx.x;
    const int m0   = bid * BM;
    const int wave = tid >> 6;
    const int lane = tid & 63;
    const int wn   = wave * 64;          // 8 waves cover N=512
    const int l15  = lane & 15;
    const int quad = lane >> 4;
    const int swz  = (l15 >> 1) & 3;
    const int aoff = l15 * BK + (quad ^ swz) * 8;

    // featurize: thread owns (row rA, 4 i's at octant q4 of the 32-chunk)
    const int rA = tid >> 3;             // 0..63
    const int q4 = tid & 7;
    const float* xrow = x + (size_t)(m0 + rA) * D_DIM + q4 * 4;
    // 8B write at 16B-slot (q4>>1) XOR-swizzled to match aoff's read swizzle
    const int awo = rA * BK + (((q4 >> 1) ^ ((rA >> 1) & 3)) * 8) + (q4 & 1) * 4;

    // per-lane B-frag base; + tIdx*16384 + jn*512 (bf16 units) per step
    const bf16* gBf = Wf + ((size_t)((wn >> 4) * 64 + lane)) * 8;

    bf16* const AsArr[8] = {As0, As1, As2, As3, As4, As5, As6, As7};

    f32x4 acc[4][4] = {};
    bf16x8 br0[4], br1[4], br2[4];   // B-frag triple buffer (idx = t mod 3 = f mod 3)
    bf16x8 afE[4], afO[4];           // A-frag pair (even step reads both)
    uint32_t vpk[2][4][4];           // [chunk parity][channel-pair][element 0..3]
    float xe[4];

    auto loadB = [&](bf16x8 (&dst)[4], int tIdx) {
        const bf16* src = gBf + (size_t)tIdx * 16384;
#pragma unroll
        for (int jn = 0; jn < 4; jn++)
            dst[jn] = *(const bf16x8*)(src + jn * 512);
    };
    auto write_pack = [&](bf16* slab, const uint32_t (&P)[4][4], int j) {
        const int pr = j >> 1;
        uint32_t o[2];
#pragma unroll
        for (int m = 0; m < 2; m++) {
            uint32_t lo = P[pr][2*m], hi = P[pr][2*m+1];
            o[m] = (j & 1) ? ((lo >> 16) | (hi & 0xFFFF0000u))
                           : ((lo & 0xFFFFu) | (hi << 16));
        }
        *(uint2*)(slab + awo) = *(const uint2*)o;
    };
    auto write_silu = [&](bf16* slab) {
        float sl[4];
#pragma unroll
        for (int e = 0; e < 4; e++)
            sl[e] = xe[e] * __builtin_amdgcn_rcpf(1.0f + __expf(-xe[e]));
        uint32_t o[2] = {pk2(sl[0],sl[1]), pk2(sl[2],sl[3])};
        *(uint2*)(slab + awo) = *(const uint2*)o;
    };
    auto domfma = [&](bf16x8 (&a)[4], bf16x8 (&b)[4]) {
        __builtin_amdgcn_s_setprio(1);
#pragma unroll
        for (int im = 0; im < 4; im++)
#pragma unroll
            for (int jn = 0; jn < 4; jn++)
                acc[im][jn] = __builtin_amdgcn_mfma_f32_16x16x32_bf16(
                    a[im], b[jn], acc[im][jn], 0, 0, 0);
        __builtin_amdgcn_s_setprio(0);
    };

    // ---- prologue: x c0; features c0; slabs 0..3 = {silu, ch0, ch1, ch2};
    //      B loads for t=0 (br0) and t=1 (br1) ----
    {
        loadB(br0, 0);                // (f=0,c=0) -> tIdx 0
        loadB(br1, 16);               // (f=1,c=0) -> tIdx 16
        float4 a = *(const float4*)xrow;
        xe[0]=a.x; xe[1]=a.y; xe[2]=a.z; xe[3]=a.w;
#pragma unroll
        for (int e = 0; e < 4; e++) {
            uint32_t o4[4];
            spline_pairs(xe[e], o4);
            vpk[0][0][e]=o4[0]; vpk[0][1][e]=o4[1];
            vpk[0][2][e]=o4[2]; vpk[0][3][e]=o4[3];
        }
        write_silu(As0);              // t=0 content
        write_pack(As1, vpk[0], 0);   // t=1: channel 0
        write_pack(As2, vpk[0], 1);   // t=2: channel 1
        write_pack(As3, vpk[0], 2);   // t=3: channel 2
        BARA;
    }

    auto step_body = [&](auto c8v, auto fv, int c) {
        constexpr int C8  = decltype(c8v)::value;   // c mod 8
        constexpr int F   = decltype(fv)::value;    // 0..8
        constexpr int PC  = C8 & 1;
        constexpr int TP  = (C8 + F) & 1;           // step parity (t mod 2)
        constexpr int ARE = (C8 + F) & 7;           // slab for t
        constexpr int ARO = (C8 + F + 1) & 7;       // slab for t+1
        constexpr int AW  = (C8 + F + 4) & 7;       // As write = (t+4) mod 8
        constexpr int BR  = F % 3;                  // B read buffer
        constexpr int BW  = (F + 2) % 3;            // B load buffer (for t+2)

        // (0) x prefetch for chunk c+1
        if (F == 0 && c < 15) {
            float4 a = *(const float4*)(xrow + (c + 1) * 32);
            xe[0]=a.x; xe[1]=a.y; xe[2]=a.z; xe[3]=a.w;
        }
        // (1) B-frag loads for step t+2 (triple buffer, distance 2)
        if (!(c == 15 && F >= 7)) {
            const int tN = (F <= 6) ? ((F + 2) * 16 + c)
                         : (F == 7) ? (c + 1)            // (c+1, f=0)
                                    : (16 + c + 1);      // (c+1, f=1)
            if constexpr (BW == 0)      loadB(br0, tN);
            else if constexpr (BW == 1) loadB(br1, tN);
            else                        loadB(br2, tN);
        }
        // (2) A-frag pair ds_reads at even steps only (t and t+1)
        if constexpr (TP == 0) {
#pragma unroll
            for (int tt = 0; tt < 4; tt++)
                afE[tt] = *(const bf16x8*)(AsArr[ARE] + tt * 16 * BK + aoff);
#pragma unroll
            for (int tt = 0; tt < 4; tt++)
                afO[tt] = *(const bf16x8*)(AsArr[ARO] + tt * 16 * BK + aoff);
        }
        // (3) pipelined featurize: elem F-1 of chunk c+1 (F=1..4)
        if constexpr (F >= 1 && F <= 4) {
            if (c < 15) {
                uint32_t o4[4];
                spline_pairs(xe[F - 1], o4);
                vpk[PC ^ 1][0][F-1]=o4[0]; vpk[PC ^ 1][1][F-1]=o4[1];
                vpk[PC ^ 1][2][F-1]=o4[2]; vpk[PC ^ 1][3][F-1]=o4[3];
            }
        }
        // (4) As write for step t+4
        if constexpr (F <= 4) {
            write_pack(AsArr[AW], vpk[PC], F + 3);            // (c, F+4): ch F+3
        } else if constexpr (F == 5) {
            if (c < 15) write_silu(AsArr[AW]);                // (c+1, 0): silu
        } else {
            if (c < 15) write_pack(AsArr[AW], vpk[PC ^ 1], F - 6); // (c+1, F-5): ch F-6
        }

        // (5) MFMA cluster
        if constexpr (TP == 0) {
            if constexpr (BR == 0)      domfma(afE, br0);
            else if constexpr (BR == 1) domfma(afE, br1);
            else                        domfma(afE, br2);
        } else {
            if constexpr (BR == 0)      domfma(afO, br0);
            else if constexpr (BR == 1) domfma(afO, br1);
            else                        domfma(afO, br2);
        }

        // (6) barrier at 4-step interval ends: t mod 4 == 3
        if constexpr (((C8 + F) & 3) == 3) {
            if (!(c == 15 && F == 8)) BARA;    // final step: no barrier
        }
    };

#define IC(n) std::integral_constant<int,(n)>{}
    auto chunk_body = [&](auto c8v, int c) {
        step_body(c8v, IC(0), c); step_body(c8v, IC(1), c); step_body(c8v, IC(2), c);
        step_body(c8v, IC(3), c); step_body(c8v, IC(4), c); step_body(c8v, IC(5), c);
        step_body(c8v, IC(6), c); step_body(c8v, IC(7), c); step_body(c8v, IC(8), c);
    };

    for (int cc = 0; cc < 16; cc += 8) {
        chunk_body(IC(0), cc);
        chunk_body(IC(1), cc + 1);
        chunk_body(IC(2), cc + 2);
        chunk_body(IC(3), cc + 3);
        chunk_body(IC(4), cc + 4);
        chunk_body(IC(5), cc + 5);
        chunk_body(IC(6), cc + 6);
        chunk_body(IC(7), cc + 7);
    }
#undef IC

    // C/D layout: col = lane&15, row = quad*4 + reg   [measured m89/m91]
#pragma unroll
    for (int im = 0; im < 4; im++) {
        const int rbase = m0 + im * 16 + quad * 4;
#pragma unroll
        for (int jn = 0; jn < 4; jn++) {
            const int col = wn + jn * 16 + l15;
#pragma unroll
            for (int rr = 0; rr < 4; rr++)
                C[(size_t)(rbase + rr) * O_DIM + col] = acc[im][jn][rr];
        }
    }
}

extern "C" void kernel_launch(void* const* d_in, const int* in_sizes, int n_in,
                              void* d_out, int out_size, void* d_ws, size_t ws_size,
                              hipStream_t stream) {
    const float* x  = (const float*)d_in[0];
    const float* bw = (const float*)d_in[1];
    const float* sw = (const float*)d_in[2];
    float* out = (float*)d_out;

    const size_t Wbytes = (size_t)144 * 32 * 64 * 8 * sizeof(bf16);  // 4.7 MB
    if (ws_size < Wbytes) return;
    bf16* W = (bf16*)d_ws;

    pack_w_kernel<<<(O_DIM * 64 + 255) / 256, 256, 0, stream>>>(bw, sw, W);
    gemm_fused_kernel<<<dim3(B_ROWS / BM), dim3(512), 0, stream>>>(x, W, out);
}